// Round 5
// baseline (332.436 us; speedup 1.0000x reference)
//
#include <hip/hip_runtime.h>

typedef __attribute__((ext_vector_type(8))) short s8v;
typedef __attribute__((ext_vector_type(4))) short s4v;
typedef __attribute__((ext_vector_type(4))) float f4v;

#define DIM 2048
#define NROW 512   // 2*B
#define NB 256     // B

__device__ inline short f2bf(float f) {
    union { float f; unsigned int u; } v; v.f = f;
    unsigned int u = v.u;
    unsigned int r = (u + 0x7fffu + ((u >> 16) & 1u)) >> 16;
    return (short)r;
}

// pack two floats -> two truncated bf16 in one int (v_perm_b32).
__device__ __forceinline__ int pk_trunc(float a, float b) {
    return __builtin_amdgcn_perm(__float_as_uint(b), __float_as_uint(a), 0x07060302);
}

// ---- 1. fused: spatial mean pool (nt stream) + W1/W2 fp32->bf16 cast + stats zero ----
// Coalescing fix vs r4: thread t loads float4 at [j*1024 + t*4] so each wave
// instruction is one contiguous 1 KiB transaction (nt loads bypass caches ->
// no MSHR merging across instructions; scattered 64B segments cost BW).
// One (row,dim) pair's 64 floats = one 16-lane row of a wave -> reduce via
// quad-xor DPP + row_shr:4/8 DPP (VALU only); lane 15 of each row stores.
__global__ __launch_bounds__(256) void pool_cast(const float* __restrict__ z0,
                                                 const float* __restrict__ z1,
                                                 const float* __restrict__ W1,
                                                 const float* __restrict__ W2,
                                                 short* __restrict__ p,
                                                 short* __restrict__ w1h,
                                                 short* __restrict__ w2h,
                                                 float* __restrict__ stats) {
    int t = threadIdx.x;
    int c = blockIdx.x;
    if (c < 8192) {
        const float* src = (c < 4096) ? z0 + (long)c * 8192 : z1 + (long)(c - 4096) * 8192;
        f4v v[8];
#pragma unroll
        for (int j = 0; j < 8; ++j)
            v[j] = __builtin_nontemporal_load((const f4v*)(src + j * 1024 + t * 4));
        __builtin_amdgcn_sched_barrier(0);  // keep all 8 loads issued before the reduce
        int row = t >> 4;                   // 16-thread row = one (row,dim) pair per j
        bool wr = (t & 15) == 15;           // row_shr chain lands total in lane 15
#pragma unroll
        for (int j = 0; j < 8; ++j) {
            float s = v[j].x + v[j].y + v[j].z + v[j].w;
            int i = __float_as_int(s);
            s += __int_as_float(__builtin_amdgcn_update_dpp(i, i, 0xB1, 0xF, 0xF, false));  // ^1
            i = __float_as_int(s);
            s += __int_as_float(__builtin_amdgcn_update_dpp(i, i, 0x4E, 0xF, 0xF, false));  // ^2
            i = __float_as_int(s);
            s += __int_as_float(__builtin_amdgcn_update_dpp(i, i, 0x114, 0xF, 0xF, true));  // row_shr:4
            i = __float_as_int(s);
            s += __int_as_float(__builtin_amdgcn_update_dpp(i, i, 0x118, 0xF, 0xF, true));  // row_shr:8
            if (wr) p[c * 128 + j * 16 + row] = f2bf(s * (1.0f / 64.0f));
        }
    } else {
        int cc = c - 8192;                  // 0..4095: 2048 slabs of 2048 floats per W
        const float* w = ((cc < 2048) ? W1 : W2) + (long)(cc & 2047) * 2048;
        short* o = ((cc < 2048) ? w1h : w2h) + (long)(cc & 2047) * 2048;
        f4v x = __builtin_nontemporal_load((const f4v*)(w + t * 4));          // 1 KiB/wave-instr
        f4v y = __builtin_nontemporal_load((const f4v*)(w + 1024 + t * 4));
        int2 o1, o2;
        o1.x = pk_trunc(x.x, x.y); o1.y = pk_trunc(x.z, x.w);
        o2.x = pk_trunc(y.x, y.y); o2.y = pk_trunc(y.z, y.w);
        *(int2*)(o + t * 4) = o1;           // 8 B/lane coalesced stores
        *(int2*)(o + 1024 + t * 4) = o2;
        if (cc == 0) {                      // zero 4096-float stats buffer
#pragma unroll
            for (int k = 0; k < 16; ++k) stats[t + k * 256] = 0.f;
        }
    }
}

// XOR-swizzled LDS address (shorts), stride 256 (BK=256 legacy kernel).
__device__ __forceinline__ int swz(int r, int k) { return r * 256 + (k ^ ((r & 7) << 3)); }
// XOR-swizzled LDS address (shorts), stride 128 (BK=128 double-buffered kernel).
__device__ __forceinline__ int swz2(int r, int k) { return r * 128 + (k ^ ((r & 7) << 3)); }

// ---- 2. bf16 NT GEMM, double-buffered 2-phase (T14 async-stage) ----
__global__ __launch_bounds__(256, 1) void gemm_db(const short* __restrict__ A,
                                                  const short* __restrict__ B,
                                                  const float* __restrict__ bias,
                                                  float* __restrict__ C,
                                                  float* __restrict__ stats,
                                                  int M, int N, int K, int kChunk) {
    __shared__ short sm[2][16384];       // [buf][A(8192) | B(8192)] shorts = 64 KB
    int t = threadIdx.x;
    int n0 = blockIdx.x * 64, m0 = blockIdx.y * 64;
    int kbase = blockIdx.z * kChunk;
    long zoff = (long)blockIdx.z * M * N;
    int lane = t & 63, w = t >> 6;
    int l16 = lane & 15, quad = lane >> 4;
    int ks = w * 32;                     // this wave's K-slice inside BK=128
    f4v acc[4][4] = {};
    int srow = t >> 4;                   // 0..15 staging row (16 rows/pass)
    int skoff = (t & 15) * 8;            // 0..120 staging k-offset
    const short* aBase = &A[(long)(m0 + srow) * K + skoff];
    const short* bBase = &B[(long)(n0 + srow) * K + skoff];
    long rstride = (long)16 * K;
    int nIter = kChunk >> 7;
    s8v ra[4], rb[4];

    // prologue: stage tile 0 into buf 0
#pragma unroll
    for (int pp = 0; pp < 4; ++pp) ra[pp] = *(const s8v*)(aBase + pp * rstride + kbase);
#pragma unroll
    for (int pp = 0; pp < 4; ++pp) rb[pp] = *(const s8v*)(bBase + pp * rstride + kbase);
#pragma unroll
    for (int pp = 0; pp < 4; ++pp) *(s8v*)&sm[0][swz2(srow + pp * 16, skoff)] = ra[pp];
#pragma unroll
    for (int pp = 0; pp < 4; ++pp) *(s8v*)&sm[0][8192 + swz2(srow + pp * 16, skoff)] = rb[pp];
    __syncthreads();

    for (int it = 0; it < nIter; ++it) {
        int cur = it & 1;
        bool pf = (it + 1) < nIter;
        if (pf) {
            int k0 = kbase + (it + 1) * 128;
#pragma unroll
            for (int pp = 0; pp < 4; ++pp) ra[pp] = *(const s8v*)(aBase + pp * rstride + k0);
#pragma unroll
            for (int pp = 0; pp < 4; ++pp) rb[pp] = *(const s8v*)(bBase + pp * rstride + k0);
        }
        __builtin_amdgcn_sched_barrier(0);   // pin prefetch issue before the MFMA phase
        const short* lA = sm[cur];
        const short* lB = sm[cur] + 8192;
        s8v af[4], bf[4];
#pragma unroll
        for (int i = 0; i < 4; ++i)
            af[i] = *(const s8v*)&lA[swz2(i * 16 + l16, ks + quad * 8)];
#pragma unroll
        for (int j = 0; j < 4; ++j)
            bf[j] = *(const s8v*)&lB[swz2(j * 16 + l16, ks + quad * 8)];
#pragma unroll
        for (int i = 0; i < 4; ++i)
#pragma unroll
            for (int j = 0; j < 4; ++j)
                acc[i][j] = __builtin_amdgcn_mfma_f32_16x16x32_bf16(af[i], bf[j], acc[i][j], 0, 0, 0);
        if (pf) {
            int nb = cur ^ 1;
#pragma unroll
            for (int pp = 0; pp < 4; ++pp) *(s8v*)&sm[nb][swz2(srow + pp * 16, skoff)] = ra[pp];
#pragma unroll
            for (int pp = 0; pp < 4; ++pp) *(s8v*)&sm[nb][8192 + swz2(srow + pp * 16, skoff)] = rb[pp];
        }
        __syncthreads();
    }

    // cross-wave K reduction: each wave dumps 64x64 fp32 partial (fr aliases
    // both staging buffers), then thread t finalizes col c = t&63.
    float* fr = (float*)sm;
#pragma unroll
    for (int i = 0; i < 4; ++i)
#pragma unroll
        for (int j = 0; j < 4; ++j)
#pragma unroll
            for (int r = 0; r < 4; ++r)
                fr[w * 4096 + (i * 16 + quad * 4 + r) * 64 + j * 16 + l16] = acc[i][j][r];
    __syncthreads();
    int c = t & 63;
    int rbase = (t >> 6) * 16;
    float bv = bias ? bias[n0 + c] : 0.0f;
    float s = 0.f, q = 0.f;
#pragma unroll
    for (int r = 0; r < 16; ++r) {
        int rr = rbase + r;
        float h = fr[rr * 64 + c] + fr[4096 + rr * 64 + c]
                + fr[8192 + rr * 64 + c] + fr[12288 + rr * 64 + c] + bv;
        C[zoff + (long)(m0 + rr) * N + n0 + c] = h;
        s += h; q += h * h;
    }
    if (stats) {
        __syncthreads();
        fr[(t >> 6) * 64 + c] = s;
        fr[256 + (t >> 6) * 64 + c] = q;
        __syncthreads();
        if (t < 64) {
            float ss = fr[t] + fr[64 + t] + fr[128 + t] + fr[192 + t];
            float qq = fr[256 + t] + fr[320 + t] + fr[384 + t] + fr[448 + t];
            atomicAdd(&stats[n0 + t], ss);
            atomicAdd(&stats[2048 + n0 + t], qq);
        }
    }
}

// ---- 2b. legacy single-buffered GEMM (fp32-B capable) — small-ws fallback ----
__global__ __launch_bounds__(256) void gemm_ks(const short* __restrict__ A,
                                               const short* __restrict__ Bh,
                                               const float* __restrict__ Bf,
                                               const float* __restrict__ bias,
                                               float* __restrict__ C,
                                               float* __restrict__ stats,
                                               int M, int N, int K, int kChunk) {
    __shared__ short sm[2 * 64 * 256];   // 64 KB; aliased as fp32 for reduce
    short* lA = sm;
    short* lB = sm + 64 * 256;
    int t = threadIdx.x;
    int n0 = blockIdx.x * 64, m0 = blockIdx.y * 64;
    int kbase = blockIdx.z * kChunk;
    long zoff = (long)blockIdx.z * M * N;
    int lane = t & 63, w = t >> 6;
    int l16 = lane & 15, quad = lane >> 4;
    int ks = w * 64;
    f4v acc[4][4] = {};
    int sr = t >> 3;
    int sq8 = (t & 7) * 8;

    for (int it = 0; it < kChunk; it += 256) {
        int k0 = kbase + it;
#pragma unroll
        for (int pp = 0; pp < 2; ++pp) {
            int r = sr + pp * 32;
            const short* as = &A[(long)(m0 + r) * K + k0];
#pragma unroll
            for (int j = 0; j < 4; ++j)
                *(s8v*)&lA[swz(r, sq8 + j * 64)] = *(const s8v*)&as[sq8 + j * 64];
        }
        if (Bh) {
#pragma unroll
            for (int pp = 0; pp < 2; ++pp) {
                int r = sr + pp * 32;
                const short* bs = &Bh[(long)(n0 + r) * K + k0];
#pragma unroll
                for (int j = 0; j < 4; ++j)
                    *(s8v*)&lB[swz(r, sq8 + j * 64)] = *(const s8v*)&bs[sq8 + j * 64];
            }
        } else {
#pragma unroll
            for (int pp = 0; pp < 2; ++pp) {
                int r = sr + pp * 32;
                const float* bs = &Bf[(long)(n0 + r) * K + k0];
#pragma unroll
                for (int j = 0; j < 4; ++j) {
                    float4 x = *(const float4*)&bs[sq8 + j * 64];
                    float4 y = *(const float4*)&bs[sq8 + j * 64 + 4];
                    int4 o;
                    o.x = pk_trunc(x.x, x.y);
                    o.y = pk_trunc(x.z, x.w);
                    o.z = pk_trunc(y.x, y.y);
                    o.w = pk_trunc(y.z, y.w);
                    *(int4*)&lB[swz(r, sq8 + j * 64)] = o;
                }
            }
        }
        __syncthreads();
#pragma unroll
        for (int kk = 0; kk < 2; ++kk) {
            s8v af[4], bf[4];
#pragma unroll
            for (int i = 0; i < 4; ++i)
                af[i] = *(const s8v*)&lA[swz(i * 16 + l16, ks + kk * 32 + quad * 8)];
#pragma unroll
            for (int j = 0; j < 4; ++j)
                bf[j] = *(const s8v*)&lB[swz(j * 16 + l16, ks + kk * 32 + quad * 8)];
#pragma unroll
            for (int i = 0; i < 4; ++i)
#pragma unroll
                for (int j = 0; j < 4; ++j)
                    acc[i][j] = __builtin_amdgcn_mfma_f32_16x16x32_bf16(af[i], bf[j], acc[i][j], 0, 0, 0);
        }
        __syncthreads();
    }

    float* fr = (float*)sm;
#pragma unroll
    for (int i = 0; i < 4; ++i)
#pragma unroll
        for (int j = 0; j < 4; ++j)
#pragma unroll
            for (int r = 0; r < 4; ++r)
                fr[w * 4096 + (i * 16 + quad * 4 + r) * 64 + j * 16 + l16] = acc[i][j][r];
    __syncthreads();
    int c = t & 63;
    int rbase = (t >> 6) * 16;
    float bv = bias ? bias[n0 + c] : 0.0f;
    float s = 0.f, q = 0.f;
#pragma unroll
    for (int r = 0; r < 16; ++r) {
        int rr = rbase + r;
        float h = fr[rr * 64 + c] + fr[4096 + rr * 64 + c]
                + fr[8192 + rr * 64 + c] + fr[12288 + rr * 64 + c] + bv;
        C[zoff + (long)(m0 + rr) * N + n0 + c] = h;
        s += h; q += h * h;
    }
    if (stats) {
        __syncthreads();
        fr[(t >> 6) * 64 + c] = s;
        fr[256 + (t >> 6) * 64 + c] = q;
        __syncthreads();
        if (t < 64) {
            float ss = fr[t] + fr[64 + t] + fr[128 + t] + fr[192 + t];
            float qq = fr[256 + t] + fr[320 + t] + fr[384 + t] + fr[448 + t];
            atomicAdd(&stats[n0 + t], ss);
            atomicAdd(&stats[2048 + n0 + t], qq);
        }
    }
}

// ---- 3. bn finalize+apply+relu+cast bf16 ----
__global__ __launch_bounds__(256) void bn_relu_cast(const float* __restrict__ h,
                                                    const float* __restrict__ stats,
                                                    const float* __restrict__ gamma,
                                                    const float* __restrict__ beta,
                                                    short* __restrict__ hn) {
    int idx = (blockIdx.x * 256 + threadIdx.x) * 4;
    int col = idx & (DIM - 1);
    float4 s0 = *(const float4*)(stats + col);
    float4 s1 = *(const float4*)(stats + 2048 + col);
    float4 g  = *(const float4*)(gamma + col);
    float4 bt = *(const float4*)(beta + col);
    float4 v  = *(const float4*)(h + idx);
    float mu, var, sc, sh;
    s4v o;
    mu = s0.x * (1.0f / NROW); var = s1.x * (1.0f / NROW) - mu * mu;
    sc = g.x * rsqrtf(var + 1e-5f); sh = bt.x - mu * sc;
    o.x = f2bf(fmaxf(v.x * sc + sh, 0.f));
    mu = s0.y * (1.0f / NROW); var = s1.y * (1.0f / NROW) - mu * mu;
    sc = g.y * rsqrtf(var + 1e-5f); sh = bt.y - mu * sc;
    o.y = f2bf(fmaxf(v.y * sc + sh, 0.f));
    mu = s0.z * (1.0f / NROW); var = s1.z * (1.0f / NROW) - mu * mu;
    sc = g.z * rsqrtf(var + 1e-5f); sh = bt.z - mu * sc;
    o.z = f2bf(fmaxf(v.z * sc + sh, 0.f));
    mu = s0.w * (1.0f / NROW); var = s1.w * (1.0f / NROW) - mu * mu;
    sc = g.w * rsqrtf(var + 1e-5f); sh = bt.w - mu * sc;
    o.w = f2bf(fmaxf(v.w * sc + sh, 0.f));
    *(s4v*)(hn + idx) = o;
}

// ---- 4. row L2 normalize + cast bf16; block 0 zeroes the loss accumulators ----
__global__ __launch_bounds__(256) void rownorm(const float* __restrict__ z,
                                               short* __restrict__ zn,
                                               float* __restrict__ out) {
    __shared__ float red[4];
    int row = blockIdx.x, t = threadIdx.x;
    if (row == 0 && t == 0) { out[0] = 0.f; out[1] = 0.f; }
    const float* zr = z + (long)row * DIM;
    float4 v0 = *(const float4*)(zr + t * 4);
    float4 v1 = *(const float4*)(zr + 1024 + t * 4);
    float ss = v0.x * v0.x + v0.y * v0.y + v0.z * v0.z + v0.w * v0.w
             + v1.x * v1.x + v1.y * v1.y + v1.z * v1.z + v1.w * v1.w;
#pragma unroll
    for (int m = 1; m < 64; m <<= 1) ss += __shfl_xor(ss, m);
    if ((t & 63) == 0) red[t >> 6] = ss;
    __syncthreads();
    float tot = red[0] + red[1] + red[2] + red[3];
    float inv = 1.0f / fmaxf(sqrtf(tot), 1e-8f);
    s4v a, b;
    a.x = f2bf(v0.x * inv); a.y = f2bf(v0.y * inv); a.z = f2bf(v0.z * inv); a.w = f2bf(v0.w * inv);
    b.x = f2bf(v1.x * inv); b.y = f2bf(v1.y * inv); b.z = f2bf(v1.z * inv); b.w = f2bf(v1.w * inv);
    *(s4v*)(zn + (long)row * DIM + t * 4) = a;
    *(s4v*)(zn + (long)row * DIM + 1024 + t * 4) = b;
}

// ---- 5. fused split-K sum + loss ----
__global__ __launch_bounds__(256) void loss_fused(const float* __restrict__ simp,
                                                  const int* __restrict__ rel,
                                                  float* __restrict__ out) {
    __shared__ float red[4], rts[4], rct[4];
    int i = blockIdx.x, t = threadIdx.x, lane = t & 63, wave = t >> 6;
    int reli = rel[i];
    float s0 = 0.f, s1 = 0.f;
#pragma unroll
    for (int z = 0; z < 8; ++z) {
        s0 += simp[(long)z * 131072 + i * 512 + t];
        s1 += simp[(long)z * 131072 + i * 512 + 256 + t];
    }
    float e0 = __expf(10.0f * s0);
    float e1 = __expf(10.0f * s1);
    int d = abs(reli - rel[t]);
    float neg = e1 + ((d > 2) ? e0 : 0.f);
#pragma unroll
    for (int m = 1; m < 64; m <<= 1) neg += __shfl_xor(neg, m);
    if (lane == 0) red[wave] = neg;
    __syncthreads();
    neg = red[0] + red[1] + red[2] + red[3];
    float ts = 0.f, cnt = 0.f;
    if (t != i && d <= 2) { ts = logf(e0 + neg) - 10.0f * s0; cnt = 1.f; }
#pragma unroll
    for (int m = 1; m < 64; m <<= 1) { ts += __shfl_xor(ts, m); cnt += __shfl_xor(cnt, m); }
    if (lane == 0) { rts[wave] = ts; rct[wave] = cnt; }
    __syncthreads();
    if (t == 0) {
        float T = rts[0] + rts[1] + rts[2] + rts[3];
        float C = rct[0] + rct[1] + rct[2] + rct[3];
        atomicAdd(&out[0], C > 0.f ? T / C : 0.f);
        atomicAdd(&out[1], C > 0.f ? 1.f : 0.f);
    }
}

extern "C" void kernel_launch(void* const* d_in, const int* in_sizes, int n_in,
                              void* d_out, int out_size, void* d_ws, size_t ws_size,
                              hipStream_t stream) {
    const float* z0    = (const float*)d_in[0];
    const float* z1    = (const float*)d_in[1];
    const int*   rel0  = (const int*)d_in[2];
    const float* W1    = (const float*)d_in[4];
    const float* b1    = (const float*)d_in[5];
    const float* gamma = (const float*)d_in[6];
    const float* beta  = (const float*)d_in[7];
    const float* W2    = (const float*)d_in[8];
    const float* b2    = (const float*)d_in[9];

    char* ws = (char*)d_ws;
    short* p_bf  = (short*)(ws);                         // 2 MB
    float* h     = (float*)(ws + (2l  << 20));           // 4 MB
    short* hn    = (short*)(ws + (6l  << 20));           // 2 MB
    float* zproj = (float*)(ws + (8l  << 20));           // 4 MB
    short* zn    = (short*)(ws + (12l << 20));           // 2 MB
    float* simp  = (float*)(ws + (14l << 20));           // 4 MB (8 x 512 KB)
    float* stats = (float*)(ws + (19l << 20));           // 16 KB (sum | sumsq)
    short* w1h   = (short*)(ws + (20l << 20));           // 8 MB bf16 W1
    short* w2h   = (short*)(ws + (28l << 20));           // 8 MB bf16 W2
    bool castok = ws_size >= (36l << 20);

    if (castok) {
        pool_cast<<<12288, 256, 0, stream>>>(z0, z1, W1, W2, p_bf, w1h, w2h, stats);
        gemm_db<<<dim3(32, 8, 1), 256, 0, stream>>>(p_bf, w1h, b1, h, stats,
                                                    NROW, DIM, DIM, DIM);
        bn_relu_cast<<<1024, 256, 0, stream>>>(h, stats, gamma, beta, hn);
        gemm_db<<<dim3(32, 8, 1), 256, 0, stream>>>(hn, w2h, b2, zproj, nullptr,
                                                    NROW, DIM, DIM, DIM);
        rownorm<<<512, 256, 0, stream>>>(zproj, zn, (float*)d_out);
        gemm_db<<<dim3(8, 4, 8), 256, 0, stream>>>(zn, zn, nullptr, simp, nullptr,
                                                   NB, NROW, DIM, 256);
        loss_fused<<<NB, 256, 0, stream>>>(simp, rel0, (float*)d_out);
    } else {
        hipMemsetAsync(stats, 0, 16384, stream);
        pool_cast<<<8192, 256, 0, stream>>>(z0, z1, nullptr, nullptr, p_bf,
                                            nullptr, nullptr, nullptr);
        gemm_ks<<<dim3(32, 8, 1), 256, 0, stream>>>(p_bf, nullptr, W1, b1, h, stats,
                                                    NROW, DIM, DIM, DIM);
        bn_relu_cast<<<1024, 256, 0, stream>>>(h, stats, gamma, beta, hn);
        gemm_ks<<<dim3(32, 8, 1), 256, 0, stream>>>(hn, nullptr, W2, b2, zproj, nullptr,
                                                    NROW, DIM, DIM, DIM);
        rownorm<<<512, 256, 0, stream>>>(zproj, zn, (float*)d_out);
        gemm_ks<<<dim3(8, 4, 8), 256, 0, stream>>>(zn, zn, nullptr, nullptr, simp, nullptr,
                                                   NB, NROW, DIM, 256);
        loss_fused<<<NB, 256, 0, stream>>>(simp, rel0, (float*)d_out);
    }
}